// Round 8
// baseline (564.239 us; speedup 1.0000x reference)
//
#include <hip/hip_runtime.h>

// ---------------- problem constants ----------------
#define N0 262144
#define N1 32768
#define N2 4096
#define EPSBN 1e-5f

typedef unsigned short ush_t;
typedef __bf16 bf16x8 __attribute__((ext_vector_type(8)));
typedef float  f32x4  __attribute__((ext_vector_type(4)));

union ufcast { unsigned int u; float f; };
__device__ __forceinline__ float bflo(unsigned int p) { ufcast x; x.u = p << 16;          return x.f; }
__device__ __forceinline__ float bfhi(unsigned int p) { ufcast x; x.u = p & 0xffff0000u; return x.f; }
__device__ __forceinline__ ush_t f2bf(float f) {
    ufcast x; x.f = f;
    unsigned int u = x.u + 0x7fffu + ((x.u >> 16) & 1u);
    return (ush_t)(u >> 16);
}
__device__ __forceinline__ bf16x8 as_bf8(uint4 u) {
    union { uint4 u; bf16x8 b; } x; x.u = u; return x.b;
}

// ---------------- weight prep: W[K][CIN][COUT] f32 -> Wb[chunk][COUTP][32] bf16 ----------------
template<int K, int CIN, int CINP_W, int COUT, int COUTP, int NCH>
__device__ __forceinline__ void prep_stage(const float* __restrict__ W, ush_t* __restrict__ Wb, int e) {
    const int k  = e & 31;
    const int n  = (e >> 5) % COUTP;
    const int ch = e / (32 * COUTP);
    const int kp = ch * 32 + k;
    const int t  = kp / CINP_W;
    const int c  = kp % CINP_W;
    float v = 0.f;
    if (t < K && c < CIN && n < COUT) v = W[((size_t)t * CIN + c) * COUT + n];
    Wb[e] = f2bf(v);
}

__global__ __launch_bounds__(256) void prep_weights(
    const float* w0, const float* wd0, const float* w1, const float* wd1, const float* wp,
    ush_t* wbA, ush_t* wbB, ush_t* wbC, ush_t* wbD, ush_t* wbE)
{
    const int e = blockIdx.x * 256 + threadIdx.x;
    switch (blockIdx.y) {
        case 0: if (e <   4096) prep_stage<27,  3,  4, 24, 32,  4>(w0,  wbA, e); break;
        case 1: if (e <  12288) prep_stage< 8, 24, 32, 48, 48,  8>(wd0, wbB, e); break;
        case 2: if (e <  82944) prep_stage<27, 48, 64, 48, 48, 54>(w1,  wbC, e); break;
        case 3: if (e <  49152) prep_stage< 8, 48, 64, 96, 96, 16>(wd1, wbD, e); break;
        case 4: if (e < 248832) prep_stage<27, 96, 96, 96, 96, 81>(wp,  wbE, e); break;
    }
}

// ---------------- input prep: data [N0,3] f32 -> XA [N0,4] bf16 ----------------
__global__ void prep_input(const float* __restrict__ data, ush_t* __restrict__ xa, int n)
{
    int m = blockIdx.x * blockDim.x + threadIdx.x;
    if (m >= n) return;
    const float* dp = data + (size_t)3 * m;
    unsigned int h0 = f2bf(dp[0]), h1 = f2bf(dp[1]), h2 = f2bf(dp[2]);
    uint2 v; v.x = h0 | (h1 << 16); v.y = h2;
    ((uint2*)xa)[m] = v;
}

// ---------------- stage A: MFMA conv + fused stats + in-kernel finalize ----------------
__global__ __launch_bounds__(256) void mconvA(
    const ush_t* __restrict__ xa,     // [N0,4] bf16
    const int*   __restrict__ neigh,  // [N0,27]
    const ush_t* __restrict__ Wb,     // [4][32][32] bf16
    ush_t*       __restrict__ y,      // [N0,24] bf16 (pre-BN)
    float*       __restrict__ bins,   // [16][48]
    int*         __restrict__ counter,
    const float* __restrict__ gamma_, const float* __restrict__ beta_,
    float*       __restrict__ ss_out) // [48]
{
    __shared__ int nl[64][29];
    __shared__ float lsq[48];
    __shared__ int lastflag;
    const int tid = threadIdx.x;
    const int block0 = blockIdx.x * 64;

    for (int i = tid; i < 64 * 27; i += 256)
        nl[i / 27][i % 27] = neigh[(size_t)(block0 + i / 27) * 27 + (i % 27)];
    if (tid < 48) lsq[tid] = 0.f;
    __syncthreads();

    const int lane = tid & 63, wave = tid >> 6;
    const int quad = lane >> 4, l15 = lane & 15;
    const int lr = wave * 16 + l15;

    f32x4 acc[2] = {};
#pragma unroll
    for (int ch = 0; ch < 4; ++ch) {
        const int tA = ch * 8 + quad * 2;
        uint4 au = make_uint4(0, 0, 0, 0);
        if (ch < 3) {
            const uint2 lo = ((const uint2*)xa)[nl[lr][tA]];
            const uint2 hi = ((const uint2*)xa)[nl[lr][tA + 1]];
            au = make_uint4(lo.x, lo.y, hi.x, hi.y);
        } else {
            if (quad == 0) {
                const uint2 lo = ((const uint2*)xa)[nl[lr][24]];
                const uint2 hi = ((const uint2*)xa)[nl[lr][25]];
                au = make_uint4(lo.x, lo.y, hi.x, hi.y);
            } else if (quad == 1) {
                const uint2 lo = ((const uint2*)xa)[nl[lr][26]];
                au = make_uint4(lo.x, lo.y, 0, 0);
            }
        }
        const bf16x8 af = as_bf8(au);
#pragma unroll
        for (int ct = 0; ct < 2; ++ct) {
            const int n = ct * 16 + l15;
            const uint4 bu = *(const uint4*)(Wb + ((size_t)ch * 32 + n) * 32 + quad * 8);
            acc[ct] = __builtin_amdgcn_mfma_f32_16x16x32_bf16(af, as_bf8(bu), acc[ct], 0, 0, 0);
        }
    }

#pragma unroll
    for (int ct = 0; ct < 2; ++ct) {
        const int col = ct * 16 + l15;
        if (col < 24) {
            float s = 0.f, q = 0.f;
#pragma unroll
            for (int r = 0; r < 4; ++r) {
                const float v = acc[ct][r];
                const int rr = block0 + wave * 16 + quad * 4 + r;
                y[(size_t)rr * 24 + col] = f2bf(v);
                s += v; q += v * v;
            }
            atomicAdd(&lsq[col], s);
            atomicAdd(&lsq[24 + col], q);
        }
    }
    __syncthreads();
    if (tid < 48) atomicAdd(&bins[(blockIdx.x & 15) * 48 + tid], lsq[tid]);
    if (tid == 0) {
        __threadfence();
        int p = __hip_atomic_fetch_add(counter, 1, __ATOMIC_ACQ_REL, __HIP_MEMORY_SCOPE_AGENT);
        lastflag = (p == (int)gridDim.x - 1) ? 1 : 0;
    }
    __syncthreads();
    if (lastflag && tid < 24) {
        float S = 0.f, Q = 0.f;
        for (int b2 = 0; b2 < 16; ++b2) {
            S += __hip_atomic_load(&bins[b2 * 48 + tid],      __ATOMIC_RELAXED, __HIP_MEMORY_SCOPE_AGENT);
            Q += __hip_atomic_load(&bins[b2 * 48 + 24 + tid], __ATOMIC_RELAXED, __HIP_MEMORY_SCOPE_AGENT);
        }
        const float mu  = S / (float)N0;
        const float var = fmaxf(Q / (float)N0 - mu * mu, 0.f);
        const float scale = gamma_[tid] / sqrtf(var + EPSBN);
        ss_out[tid]      = scale;
        ss_out[24 + tid] = beta_[tid] - mu * scale;
    }
}

// ---------------- stage B: gather y0 bf16 + fused BN/ReLU -> MFMA ----------------
__global__ __launch_bounds__(256) void mconvB(
    const ush_t* __restrict__ y0,     // [N0,24] bf16 pre-BN
    const float* __restrict__ ss,     // [48]
    const int*   __restrict__ child,  // [N1,8]
    const ush_t* __restrict__ Wb,     // [8][48][32]
    float*       __restrict__ yout, size_t ystride)
{
    const int tid = threadIdx.x;
    const int lane = tid & 63, wave = tid >> 6;
    const int quad = lane >> 4, l15 = lane & 15;
    const int kg = blockIdx.y;
    const int rowA = blockIdx.x * 64 + wave * 16 + l15;
    const int c0 = quad * 8;

    float sc[8], sh[8];
    if (c0 < 24) {
#pragma unroll
        for (int j = 0; j < 8; ++j) { sc[j] = ss[c0 + j]; sh[j] = ss[24 + c0 + j]; }
    }

    f32x4 acc[3] = {};
#pragma unroll
    for (int ci = 0; ci < 4; ++ci) {
        const int t = kg * 4 + ci;
        const int idx = child[(size_t)rowA * 8 + t];
        uint4 au = make_uint4(0, 0, 0, 0);
        if (c0 < 24) {
            const uint4 raw = *(const uint4*)(y0 + (size_t)idx * 24 + c0);
            const unsigned int w4[4] = {raw.x, raw.y, raw.z, raw.w};
            unsigned int o4[4];
#pragma unroll
            for (int h = 0; h < 4; ++h) {
                const float a0 = fmaxf(bflo(w4[h]) * sc[2 * h]     + sh[2 * h],     0.f);
                const float a1 = fmaxf(bfhi(w4[h]) * sc[2 * h + 1] + sh[2 * h + 1], 0.f);
                o4[h] = (unsigned)f2bf(a0) | ((unsigned)f2bf(a1) << 16);
            }
            au = make_uint4(o4[0], o4[1], o4[2], o4[3]);
        }
        const bf16x8 af = as_bf8(au);
#pragma unroll
        for (int ct = 0; ct < 3; ++ct) {
            const int n = ct * 16 + l15;
            const uint4 bu = *(const uint4*)(Wb + ((size_t)(kg * 4 + ci) * 48 + n) * 32 + quad * 8);
            acc[ct] = __builtin_amdgcn_mfma_f32_16x16x32_bf16(af, as_bf8(bu), acc[ct], 0, 0, 0);
        }
    }

    float* yo = yout + (size_t)kg * ystride;
#pragma unroll
    for (int ct = 0; ct < 3; ++ct) {
        const int col = ct * 16 + l15;
#pragma unroll
        for (int r = 0; r < 4; ++r) {
            const int rr = blockIdx.x * 64 + wave * 16 + quad * 4 + r;
            yo[(size_t)rr * 48 + col] = acc[ct][r];
        }
    }
}

// ---------------- generic MFMA conv (bf16 activated input), stages C and E ----------------
template<int K, int CIN, int CINP, int COUT, int COUTP, int NCHT, int KG, int CG>
__global__ __launch_bounds__(256) void mconv(
    const ush_t* __restrict__ xb,
    const int*   __restrict__ neigh,
    const ush_t* __restrict__ Wb,
    float*       __restrict__ yout,
    size_t       ystride, int M)
{
    constexpr int NCH = NCHT / KG;
    constexpr int NCT = (COUTP / 16) / CG;
    constexpr int CPT = CINP / 32;
    const int lane = threadIdx.x & 63;
    const int wave = threadIdx.x >> 6;
    const int quad = lane >> 4, l15 = lane & 15;
    const int kg = blockIdx.y, cg = blockIdx.z;
    const int rowA = blockIdx.x * 64 + wave * 16 + l15;

    f32x4 acc[NCT] = {};

#pragma unroll
    for (int ci = 0; ci < NCH; ++ci) {
        const int ch  = kg * NCH + ci;
        const int t   = ch / CPT;
        const int sub = ch % CPT;
        const int idx = neigh[(size_t)rowA * K + t];
        const uint4 au = *(const uint4*)(xb + (size_t)idx * CINP + sub * 32 + quad * 8);
        const bf16x8 af = as_bf8(au);
#pragma unroll
        for (int ct = 0; ct < NCT; ++ct) {
            const int n = (cg * NCT + ct) * 16 + l15;
            const uint4 bu = *(const uint4*)(Wb + ((size_t)ch * COUTP + n) * 32 + quad * 8);
            acc[ct] = __builtin_amdgcn_mfma_f32_16x16x32_bf16(af, as_bf8(bu), acc[ct], 0, 0, 0);
        }
    }

    float* yo = yout + (size_t)kg * ystride;
#pragma unroll
    for (int ct = 0; ct < NCT; ++ct) {
        const int col = (cg * NCT + ct) * 16 + l15;
#pragma unroll
        for (int r = 0; r < 4; ++r) {
            const int rr = blockIdx.x * 64 + wave * 16 + quad * 4 + r;
            yo[(size_t)rr * COUT + col] = acc[ct][r];
        }
    }
}

// ---------------- stage D: gather y2 f32 + fused BN/ReLU -> MFMA ----------------
__global__ __launch_bounds__(256) void mconvD(
    const float* __restrict__ y2,     // [N1,48] f32
    const float* __restrict__ ss,     // [96]
    const int*   __restrict__ child,  // [N2,8]
    const ush_t* __restrict__ Wb,     // [16][96][32]
    float*       __restrict__ yout, size_t ystride)
{
    const int tid = threadIdx.x;
    const int lane = tid & 63, wave = tid >> 6;
    const int quad = lane >> 4, l15 = lane & 15;
    const int kg = blockIdx.y, cg = blockIdx.z;
    const int rowA = blockIdx.x * 64 + wave * 16 + l15;
    const int c0a = quad * 8;        // sub 0: always < 48
    const int c0b = 32 + quad * 8;   // sub 1: real iff quad < 2

    float sca[8], sha[8], scb[8], shb[8];
#pragma unroll
    for (int j = 0; j < 8; ++j) { sca[j] = ss[c0a + j]; sha[j] = ss[48 + c0a + j]; }
    if (quad < 2) {
#pragma unroll
        for (int j = 0; j < 8; ++j) { scb[j] = ss[c0b + j]; shb[j] = ss[48 + c0b + j]; }
    }

    f32x4 acc[2] = {};
#pragma unroll
    for (int ci = 0; ci < 4; ++ci) {
        const int ch  = kg * 4 + ci;
        const int t   = ch >> 1;
        const int sub = ch & 1;
        const int idx = child[(size_t)rowA * 8 + t];
        uint4 au = make_uint4(0, 0, 0, 0);
        const int c0 = sub ? c0b : c0a;
        if (c0 < 48) {
            const float4 v0 = *(const float4*)(y2 + (size_t)idx * 48 + c0);
            const float4 v1 = *(const float4*)(y2 + (size_t)idx * 48 + c0 + 4);
            const float vv[8] = {v0.x, v0.y, v0.z, v0.w, v1.x, v1.y, v1.z, v1.w};
            const float* scp = sub ? scb : sca;
            const float* shp = sub ? shb : sha;
            unsigned int o4[4];
#pragma unroll
            for (int h = 0; h < 4; ++h) {
                const float a0 = fmaxf(vv[2 * h]     * scp[2 * h]     + shp[2 * h],     0.f);
                const float a1 = fmaxf(vv[2 * h + 1] * scp[2 * h + 1] + shp[2 * h + 1], 0.f);
                o4[h] = (unsigned)f2bf(a0) | ((unsigned)f2bf(a1) << 16);
            }
            au = make_uint4(o4[0], o4[1], o4[2], o4[3]);
        }
        const bf16x8 af = as_bf8(au);
#pragma unroll
        for (int ct = 0; ct < 2; ++ct) {
            const int n = (cg * 2 + ct) * 16 + l15;
            const uint4 bu = *(const uint4*)(Wb + ((size_t)ch * 96 + n) * 32 + quad * 8);
            acc[ct] = __builtin_amdgcn_mfma_f32_16x16x32_bf16(af, as_bf8(bu), acc[ct], 0, 0, 0);
        }
    }

    float* yo = yout + (size_t)kg * ystride;
#pragma unroll
    for (int ct = 0; ct < 2; ++ct) {
        const int col = (cg * 2 + ct) * 16 + l15;
#pragma unroll
        for (int r = 0; r < 4; ++r) {
            const int rr = blockIdx.x * 64 + wave * 16 + quad * 4 + r;
            yo[(size_t)rr * 96 + col] = acc[ct][r];
        }
    }
}

// ---------------- stats v2: vectorized partial-sum + moments + fused finalize ----------------
template<int C, int P, int NB>
__global__ __launch_bounds__(256) void stats2(
    const float* __restrict__ part, size_t pstride,
    float* __restrict__ yfull, int total, int M,
    const float* __restrict__ gamma_, const float* __restrict__ beta_,
    float* __restrict__ bins, int* __restrict__ counter, float* __restrict__ ss_out)
{
    __shared__ float lsq[2 * C];
    __shared__ int lastflag;
    const int tid = threadIdx.x;
    if (tid < 2 * C) lsq[tid] = 0.f;
    __syncthreads();

    float s4[4] = {0, 0, 0, 0}, q4[4] = {0, 0, 0, 0};
    int i = (blockIdx.x * 256 + tid) * 4;
    const int c0 = i % C;                       // constant: stride % C == 0
    const int stride = gridDim.x * 1024;
    for (; i < total; i += stride) {
        float4 v = *(const float4*)(part + i);
#pragma unroll
        for (int p = 1; p < P; ++p) {
            const float4 w = *(const float4*)(part + (size_t)p * pstride + i);
            v.x += w.x; v.y += w.y; v.z += w.z; v.w += w.w;
        }
        *(float4*)(yfull + i) = v;
        s4[0] += v.x; q4[0] += v.x * v.x;
        s4[1] += v.y; q4[1] += v.y * v.y;
        s4[2] += v.z; q4[2] += v.z * v.z;
        s4[3] += v.w; q4[3] += v.w * v.w;
    }
#pragma unroll
    for (int j = 0; j < 4; ++j) {
        atomicAdd(&lsq[c0 + j], s4[j]);
        atomicAdd(&lsq[C + c0 + j], q4[j]);
    }
    __syncthreads();
    if (tid < 2 * C) atomicAdd(&bins[(blockIdx.x % NB) * 2 * C + tid], lsq[tid]);
    if (tid == 0) {
        __threadfence();
        int p = __hip_atomic_fetch_add(counter, 1, __ATOMIC_ACQ_REL, __HIP_MEMORY_SCOPE_AGENT);
        lastflag = (p == (int)gridDim.x - 1) ? 1 : 0;
    }
    __syncthreads();
    if (lastflag && tid < C) {
        float S = 0.f, Q = 0.f;
        for (int b2 = 0; b2 < NB; ++b2) {
            S += __hip_atomic_load(&bins[b2 * 2 * C + tid],     __ATOMIC_RELAXED, __HIP_MEMORY_SCOPE_AGENT);
            Q += __hip_atomic_load(&bins[b2 * 2 * C + C + tid], __ATOMIC_RELAXED, __HIP_MEMORY_SCOPE_AGENT);
        }
        const float mu  = S / (float)M;
        const float var = fmaxf(Q / (float)M - mu * mu, 0.f);
        const float scale = gamma_[tid] / sqrtf(var + EPSBN);
        ss_out[tid]     = scale;
        ss_out[C + tid] = beta_[tid] - mu * scale;
    }
}

// ---------------- activation: XB = bf16(relu(y*scale+shift)), zero pad cols ----------------
template<int C, int CP>
__global__ void activate_kernel(const float* __restrict__ y, const float* __restrict__ ss,
                                ush_t* __restrict__ xb, int totalP)
{
    int i = (blockIdx.x * blockDim.x + threadIdx.x) * 4;
    if (i >= totalP) return;
    const int c = i % CP;
    ushort4 o;
    if (CP != C && c >= C) {
        o.x = o.y = o.z = o.w = 0;
    } else {
        const int r = i / CP;
        float4 v = *(const float4*)(y + (size_t)r * C + c);
        o.x = f2bf(fmaxf(v.x * ss[c + 0] + ss[C + c + 0], 0.f));
        o.y = f2bf(fmaxf(v.y * ss[c + 1] + ss[C + c + 1], 0.f));
        o.z = f2bf(fmaxf(v.z * ss[c + 2] + ss[C + c + 2], 0.f));
        o.w = f2bf(fmaxf(v.w * ss[c + 3] + ss[C + c + 3], 0.f));
    }
    *(ushort4*)(xb + i) = o;
}

// ---------------- final write (f32 out) ----------------
__global__ void writeout_kernel(const float* __restrict__ y, const float* __restrict__ ss,
                                float* __restrict__ out, int total)
{
    int i = (blockIdx.x * blockDim.x + threadIdx.x) * 4;
    if (i >= total) return;
    float4 v = *(const float4*)(y + i);
    int c = i % 96;
    float4 o;
    o.x = fmaxf(v.x * ss[c + 0] + ss[96 + c + 0], 0.f);
    o.y = fmaxf(v.y * ss[c + 1] + ss[96 + c + 1], 0.f);
    o.z = fmaxf(v.z * ss[c + 2] + ss[96 + c + 2], 0.f);
    o.w = fmaxf(v.w * ss[c + 3] + ss[96 + c + 3], 0.f);
    *(float4*)(out + i) = o;
}

// ---------------- host ----------------
extern "C" void kernel_launch(void* const* d_in, const int* in_sizes, int n_in,
                              void* d_out, int out_size, void* d_ws, size_t ws_size,
                              hipStream_t stream)
{
    const float* data   = (const float*)d_in[0];
    const int*   neigh0 = (const int*)d_in[1];
    const int*   child0 = (const int*)d_in[2];
    const int*   neigh1 = (const int*)d_in[3];
    const int*   child1 = (const int*)d_in[4];
    const int*   neigh2 = (const int*)d_in[5];
    const float* w0  = (const float*)d_in[6];
    const float* g0  = (const float*)d_in[7];
    const float* b0  = (const float*)d_in[8];
    const float* wd0 = (const float*)d_in[9];
    const float* gd0 = (const float*)d_in[10];
    const float* bd0 = (const float*)d_in[11];
    const float* w1  = (const float*)d_in[12];
    const float* g1  = (const float*)d_in[13];
    const float* b1  = (const float*)d_in[14];
    const float* wd1 = (const float*)d_in[15];
    const float* gd1 = (const float*)d_in[16];
    const float* bd1 = (const float*)d_in[17];
    const float* wp  = (const float*)d_in[18];
    const float* gp  = (const float*)d_in[19];
    const float* bp  = (const float*)d_in[20];
    float* out = (float*)d_out;

    // header (float offsets)
    float* wsf = (float*)d_ws;
    int*   counters = (int*)d_ws;      // ints [0..8)
    float* binsA = wsf + 16;           // 16*48  = 768   -> 784
    float* binsB = wsf + 784;          // 16*96  = 1536  -> 2320
    float* binsC = wsf + 2320;         // 1536           -> 3856
    float* binsD = wsf + 3856;         // 16*192 = 3072  -> 6928
    float* binsE = wsf + 6928;         // 3072           -> 10000
    float* ss0 = wsf + 10000;          // 48
    float* ss1 = wsf + 10064;          // 96
    float* ss2 = wsf + 10176;          // 96
    float* ss3 = wsf + 10288;          // 192
    float* ss4 = wsf + 10480;          // 192 -> ends 10672, pad 10752

    // arena
    float* YF   = wsf + 10752;                         // 1,572,864 f (y1/y2/y3/y4)
    float* PART = YF + (size_t)1572864;                // 3,538,944 f (partials)
    ush_t* Y0B  = (ush_t*)(PART + (size_t)3538944);    // 6,291,456 ush: y0 bf16 [N0,24]
    ush_t* XB   = Y0B + (size_t)6291456;               // 2,097,152 ush: bf16 activ. [N1,64]/[N2,96]
    ush_t* XA   = XB + (size_t)2097152;                // 1,048,576 ush: packed input [N0,4]
    ush_t* WB   = XA + (size_t)1048576;                //   524,288 ush: prepped weights

    ush_t* wbA = WB;
    ush_t* wbB = WB + 4096;
    ush_t* wbC = WB + 16384;
    ush_t* wbD = WB + 99328;
    ush_t* wbE = WB + 148480;

    hipMemsetAsync(d_ws, 0, 10752 * sizeof(float), stream);

    const size_t s1 = (size_t)N1 * 48;
    const size_t s2 = (size_t)N2 * 96;

    prep_weights<<<dim3(972, 5), 256, 0, stream>>>(w0, wd0, w1, wd1, wp, wbA, wbB, wbC, wbD, wbE);
    prep_input<<<N0 / 256, 256, 0, stream>>>(data, XA, N0);

    // stage A: fused conv+stats+finalize -> Y0B (bf16 pre-BN), ss0
    mconvA<<<N0 / 64, 256, 0, stream>>>(XA, neigh0, wbA, Y0B, binsA, &counters[0], g0, b0, ss0);

    // stage B: fused activate(y0,ss0) gather -> partials(2); stats -> y1 (YF), ss1; activate -> XB
    mconvB<<<dim3(N1 / 64, 2, 1), 256, 0, stream>>>(Y0B, ss0, child0, wbB, PART, s1);
    stats2<48, 2, 16><<<384, 256, 0, stream>>>(PART, s1, YF, N1 * 48, N1, gd0, bd0, binsB, &counters[1], ss1);
    activate_kernel<48, 64><<<N1 * 64 / 4 / 256, 256, 0, stream>>>(YF, ss1, XB, N1 * 64);

    // stage C: XB -> partials(2); stats -> y2 (YF), ss2
    mconv<27, 48, 64, 48, 48, 54, 2, 1><<<dim3(N1 / 64, 2, 1), 256, 0, stream>>>(XB, neigh1, wbC, PART, s1, N1);
    stats2<48, 2, 16><<<384, 256, 0, stream>>>(PART, s1, YF, N1 * 48, N1, g1, b1, binsC, &counters[2], ss2);

    // stage D: fused activate(y2,ss2) gather -> partials(4); stats -> y3 (YF), ss3; activate -> XB
    mconvD<<<dim3(N2 / 64, 4, 3), 256, 0, stream>>>(YF, ss2, child1, wbD, PART, s2);
    stats2<96, 4, 16><<<384, 256, 0, stream>>>(PART, s2, YF, N2 * 96, N2, gd1, bd1, binsD, &counters[3], ss3);
    activate_kernel<96, 96><<<N2 * 96 / 4 / 256, 256, 0, stream>>>(YF, ss3, XB, N2 * 96);

    // stage E: XB -> partials(9); stats -> y4 (YF), ss4
    mconv<27, 96, 96, 96, 96, 81, 9, 2><<<dim3(N2 / 64, 9, 2), 256, 0, stream>>>(XB, neigh2, wbE, PART, s2, N2);
    stats2<96, 9, 16><<<384, 256, 0, stream>>>(PART, s2, YF, N2 * 96, N2, gp, bp, binsE, &counters[4], ss4);

    // final normalize + relu -> out
    writeout_kernel<<<N2 * 96 / 4 / 256, 256, 0, stream>>>(YF, ss4, out, N2 * 96);

    (void)in_sizes; (void)n_in; (void)out_size; (void)ws_size;
}

// Round 9
// 323.212 us; speedup vs baseline: 1.7457x; 1.7457x over previous
//
#include <hip/hip_runtime.h>

// ---------------- problem constants ----------------
#define N0 262144
#define N1 32768
#define N2 4096
#define EPSBN 1e-5f

typedef unsigned short ush_t;
typedef __bf16 bf16x8 __attribute__((ext_vector_type(8)));
typedef float  f32x4  __attribute__((ext_vector_type(4)));

union ufcast { unsigned int u; float f; };
__device__ __forceinline__ float bflo(unsigned int p) { ufcast x; x.u = p << 16;          return x.f; }
__device__ __forceinline__ float bfhi(unsigned int p) { ufcast x; x.u = p & 0xffff0000u; return x.f; }
__device__ __forceinline__ ush_t f2bf(float f) {
    ufcast x; x.f = f;
    unsigned int u = x.u + 0x7fffu + ((x.u >> 16) & 1u);
    return (ush_t)(u >> 16);
}
__device__ __forceinline__ bf16x8 as_bf8(uint4 u) {
    union { uint4 u; bf16x8 b; } x; x.u = u; return x.b;
}

// ---------------- weight prep: W[K][CIN][COUT] f32 -> Wb[chunk][COUTP][32] bf16 ----------------
template<int K, int CIN, int CINP_W, int COUT, int COUTP, int NCH>
__device__ __forceinline__ void prep_stage(const float* __restrict__ W, ush_t* __restrict__ Wb, int e) {
    const int k  = e & 31;
    const int n  = (e >> 5) % COUTP;
    const int ch = e / (32 * COUTP);
    const int kp = ch * 32 + k;
    const int t  = kp / CINP_W;
    const int c  = kp % CINP_W;
    float v = 0.f;
    if (t < K && c < CIN && n < COUT) v = W[((size_t)t * CIN + c) * COUT + n];
    Wb[e] = f2bf(v);
}

__global__ __launch_bounds__(256) void prep_weights(
    const float* w0, const float* wd0, const float* w1, const float* wd1, const float* wp,
    ush_t* wbA, ush_t* wbB, ush_t* wbC, ush_t* wbD, ush_t* wbE)
{
    const int e = blockIdx.x * 256 + threadIdx.x;
    switch (blockIdx.y) {
        case 0: if (e <   4096) prep_stage<27,  3,  4, 24, 32,  4>(w0,  wbA, e); break;
        case 1: if (e <  12288) prep_stage< 8, 24, 32, 48, 48,  8>(wd0, wbB, e); break;
        case 2: if (e <  82944) prep_stage<27, 48, 64, 48, 48, 54>(w1,  wbC, e); break;
        case 3: if (e <  49152) prep_stage< 8, 48, 64, 96, 96, 16>(wd1, wbD, e); break;
        case 4: if (e < 248832) prep_stage<27, 96, 96, 96, 96, 81>(wp,  wbE, e); break;
    }
}

// ---------------- input prep: data [N0,3] f32 -> XA [N0,4] bf16 ----------------
__global__ void prep_input(const float* __restrict__ data, ush_t* __restrict__ xa, int n)
{
    int m = blockIdx.x * blockDim.x + threadIdx.x;
    if (m >= n) return;
    const float* dp = data + (size_t)3 * m;
    unsigned int h0 = f2bf(dp[0]), h1 = f2bf(dp[1]), h2 = f2bf(dp[2]);
    uint2 v; v.x = h0 | (h1 << 16); v.y = h2;
    ((uint2*)xa)[m] = v;
}

// ---------------- stage A: MFMA conv, NO stats (coalesced neigh staging, bf16 out) ----------------
__global__ __launch_bounds__(256) void mconvA(
    const ush_t* __restrict__ xa,     // [N0,4] bf16
    const int*   __restrict__ neigh,  // [N0,27]
    const ush_t* __restrict__ Wb,     // [4][32][32] bf16
    ush_t*       __restrict__ y)      // [N0,24] bf16 (pre-BN)
{
    __shared__ int nl[64][29];
    const int tid = threadIdx.x;
    const int block0 = blockIdx.x * 64;

    for (int i = tid; i < 64 * 27; i += 256)
        nl[i / 27][i % 27] = neigh[(size_t)block0 * 27 + i];
    __syncthreads();

    const int lane = tid & 63, wave = tid >> 6;
    const int quad = lane >> 4, l15 = lane & 15;
    const int lr = wave * 16 + l15;

    f32x4 acc[2] = {};
#pragma unroll
    for (int ch = 0; ch < 4; ++ch) {
        const int tA = ch * 8 + quad * 2;
        uint4 au = make_uint4(0, 0, 0, 0);
        if (ch < 3) {
            const uint2 lo = ((const uint2*)xa)[nl[lr][tA]];
            const uint2 hi = ((const uint2*)xa)[nl[lr][tA + 1]];
            au = make_uint4(lo.x, lo.y, hi.x, hi.y);
        } else {
            if (quad == 0) {
                const uint2 lo = ((const uint2*)xa)[nl[lr][24]];
                const uint2 hi = ((const uint2*)xa)[nl[lr][25]];
                au = make_uint4(lo.x, lo.y, hi.x, hi.y);
            } else if (quad == 1) {
                const uint2 lo = ((const uint2*)xa)[nl[lr][26]];
                au = make_uint4(lo.x, lo.y, 0, 0);
            }
        }
        const bf16x8 af = as_bf8(au);
#pragma unroll
        for (int ct = 0; ct < 2; ++ct) {
            const int n = ct * 16 + l15;
            const uint4 bu = *(const uint4*)(Wb + ((size_t)ch * 32 + n) * 32 + quad * 8);
            acc[ct] = __builtin_amdgcn_mfma_f32_16x16x32_bf16(af, as_bf8(bu), acc[ct], 0, 0, 0);
        }
    }

#pragma unroll
    for (int ct = 0; ct < 2; ++ct) {
        const int col = ct * 16 + l15;
        if (col < 24) {
#pragma unroll
            for (int r = 0; r < 4; ++r) {
                const int rr = block0 + wave * 16 + quad * 4 + r;
                y[(size_t)rr * 24 + col] = f2bf(acc[ct][r]);
            }
        }
    }
}

// ---------------- statsA: bf16 y0 [N0,24] -> ss0 (small grid, binned atomics) ----------------
__global__ __launch_bounds__(256) void statsA(
    const ush_t* __restrict__ y0,
    const float* __restrict__ gamma_, const float* __restrict__ beta_,
    float* __restrict__ bins, int* __restrict__ counter, float* __restrict__ ss_out)
{
    __shared__ float lsq[48];
    __shared__ int lastflag;
    const int tid = threadIdx.x;
    if (tid < 48) lsq[tid] = 0.f;
    __syncthreads();

    const int total8 = N0 * 24 / 8;             // uint4 count = 786432
    int i = blockIdx.x * 256 + tid;
    const int stride = gridDim.x * 256;         // 98304; *8 elements % 24 == 0 -> fixed phase
    const int c0 = (i * 8) % 24;                // in {0,8,16}

    float s[8] = {0,0,0,0,0,0,0,0}, q[8] = {0,0,0,0,0,0,0,0};
    for (; i < total8; i += stride) {
        const uint4 v = ((const uint4*)y0)[i];
        const unsigned int w4[4] = {v.x, v.y, v.z, v.w};
#pragma unroll
        for (int h = 0; h < 4; ++h) {
            const float a = bflo(w4[h]), b2 = bfhi(w4[h]);
            s[2*h] += a;  q[2*h] += a * a;
            s[2*h+1] += b2; q[2*h+1] += b2 * b2;
        }
    }
#pragma unroll
    for (int j = 0; j < 8; ++j) {
        atomicAdd(&lsq[c0 + j], s[j]);
        atomicAdd(&lsq[24 + c0 + j], q[j]);
    }
    __syncthreads();
    if (tid < 48) atomicAdd(&bins[(blockIdx.x & 15) * 48 + tid], lsq[tid]);
    if (tid == 0) {
        __threadfence();
        int p = __hip_atomic_fetch_add(counter, 1, __ATOMIC_ACQ_REL, __HIP_MEMORY_SCOPE_AGENT);
        lastflag = (p == (int)gridDim.x - 1) ? 1 : 0;
    }
    __syncthreads();
    if (lastflag && tid < 24) {
        float S = 0.f, Q = 0.f;
        for (int b2 = 0; b2 < 16; ++b2) {
            S += __hip_atomic_load(&bins[b2 * 48 + tid],      __ATOMIC_RELAXED, __HIP_MEMORY_SCOPE_AGENT);
            Q += __hip_atomic_load(&bins[b2 * 48 + 24 + tid], __ATOMIC_RELAXED, __HIP_MEMORY_SCOPE_AGENT);
        }
        const float mu  = S / (float)N0;
        const float var = fmaxf(Q / (float)N0 - mu * mu, 0.f);
        const float scale = gamma_[tid] / sqrtf(var + EPSBN);
        ss_out[tid]      = scale;
        ss_out[24 + tid] = beta_[tid] - mu * scale;
    }
}

// ---------------- stage B: gather y0 bf16 + fused BN/ReLU -> MFMA ----------------
__global__ __launch_bounds__(256) void mconvB(
    const ush_t* __restrict__ y0,     // [N0,24] bf16 pre-BN
    const float* __restrict__ ss,     // [48]
    const int*   __restrict__ child,  // [N1,8]
    const ush_t* __restrict__ Wb,     // [8][48][32]
    float*       __restrict__ yout, size_t ystride)
{
    const int tid = threadIdx.x;
    const int lane = tid & 63, wave = tid >> 6;
    const int quad = lane >> 4, l15 = lane & 15;
    const int kg = blockIdx.y;
    const int rowA = blockIdx.x * 64 + wave * 16 + l15;
    const int c0 = quad * 8;

    float sc[8], sh[8];
    if (c0 < 24) {
#pragma unroll
        for (int j = 0; j < 8; ++j) { sc[j] = ss[c0 + j]; sh[j] = ss[24 + c0 + j]; }
    }

    f32x4 acc[3] = {};
#pragma unroll
    for (int ci = 0; ci < 4; ++ci) {
        const int t = kg * 4 + ci;
        const int idx = child[(size_t)rowA * 8 + t];
        uint4 au = make_uint4(0, 0, 0, 0);
        if (c0 < 24) {
            const uint4 raw = *(const uint4*)(y0 + (size_t)idx * 24 + c0);
            const unsigned int w4[4] = {raw.x, raw.y, raw.z, raw.w};
            unsigned int o4[4];
#pragma unroll
            for (int h = 0; h < 4; ++h) {
                const float a0 = fmaxf(bflo(w4[h]) * sc[2 * h]     + sh[2 * h],     0.f);
                const float a1 = fmaxf(bfhi(w4[h]) * sc[2 * h + 1] + sh[2 * h + 1], 0.f);
                o4[h] = (unsigned)f2bf(a0) | ((unsigned)f2bf(a1) << 16);
            }
            au = make_uint4(o4[0], o4[1], o4[2], o4[3]);
        }
        const bf16x8 af = as_bf8(au);
#pragma unroll
        for (int ct = 0; ct < 3; ++ct) {
            const int n = ct * 16 + l15;
            const uint4 bu = *(const uint4*)(Wb + ((size_t)(kg * 4 + ci) * 48 + n) * 32 + quad * 8);
            acc[ct] = __builtin_amdgcn_mfma_f32_16x16x32_bf16(af, as_bf8(bu), acc[ct], 0, 0, 0);
        }
    }

    float* yo = yout + (size_t)kg * ystride;
#pragma unroll
    for (int ct = 0; ct < 3; ++ct) {
        const int col = ct * 16 + l15;
#pragma unroll
        for (int r = 0; r < 4; ++r) {
            const int rr = blockIdx.x * 64 + wave * 16 + quad * 4 + r;
            yo[(size_t)rr * 48 + col] = acc[ct][r];
        }
    }
}

// ---------------- generic MFMA conv (bf16 activated input), stages C and E ----------------
template<int K, int CIN, int CINP, int COUT, int COUTP, int NCHT, int KG, int CG>
__global__ __launch_bounds__(256) void mconv(
    const ush_t* __restrict__ xb,
    const int*   __restrict__ neigh,
    const ush_t* __restrict__ Wb,
    float*       __restrict__ yout,
    size_t       ystride, int M)
{
    constexpr int NCH = NCHT / KG;
    constexpr int NCT = (COUTP / 16) / CG;
    constexpr int CPT = CINP / 32;
    const int lane = threadIdx.x & 63;
    const int wave = threadIdx.x >> 6;
    const int quad = lane >> 4, l15 = lane & 15;
    const int kg = blockIdx.y, cg = blockIdx.z;
    const int rowA = blockIdx.x * 64 + wave * 16 + l15;

    f32x4 acc[NCT] = {};

#pragma unroll
    for (int ci = 0; ci < NCH; ++ci) {
        const int ch  = kg * NCH + ci;
        const int t   = ch / CPT;
        const int sub = ch % CPT;
        const int idx = neigh[(size_t)rowA * K + t];
        const uint4 au = *(const uint4*)(xb + (size_t)idx * CINP + sub * 32 + quad * 8);
        const bf16x8 af = as_bf8(au);
#pragma unroll
        for (int ct = 0; ct < NCT; ++ct) {
            const int n = (cg * NCT + ct) * 16 + l15;
            const uint4 bu = *(const uint4*)(Wb + ((size_t)ch * COUTP + n) * 32 + quad * 8);
            acc[ct] = __builtin_amdgcn_mfma_f32_16x16x32_bf16(af, as_bf8(bu), acc[ct], 0, 0, 0);
        }
    }

    float* yo = yout + (size_t)kg * ystride;
#pragma unroll
    for (int ct = 0; ct < NCT; ++ct) {
        const int col = (cg * NCT + ct) * 16 + l15;
#pragma unroll
        for (int r = 0; r < 4; ++r) {
            const int rr = blockIdx.x * 64 + wave * 16 + quad * 4 + r;
            yo[(size_t)rr * COUT + col] = acc[ct][r];
        }
    }
}

// ---------------- stage D: gather y2 f32 + fused BN/ReLU -> MFMA ----------------
__global__ __launch_bounds__(256) void mconvD(
    const float* __restrict__ y2,     // [N1,48] f32
    const float* __restrict__ ss,     // [96]
    const int*   __restrict__ child,  // [N2,8]
    const ush_t* __restrict__ Wb,     // [16][96][32]
    float*       __restrict__ yout, size_t ystride)
{
    const int tid = threadIdx.x;
    const int lane = tid & 63, wave = tid >> 6;
    const int quad = lane >> 4, l15 = lane & 15;
    const int kg = blockIdx.y, cg = blockIdx.z;
    const int rowA = blockIdx.x * 64 + wave * 16 + l15;
    const int c0a = quad * 8;
    const int c0b = 32 + quad * 8;

    float sca[8], sha[8], scb[8], shb[8];
#pragma unroll
    for (int j = 0; j < 8; ++j) { sca[j] = ss[c0a + j]; sha[j] = ss[48 + c0a + j]; }
    if (quad < 2) {
#pragma unroll
        for (int j = 0; j < 8; ++j) { scb[j] = ss[c0b + j]; shb[j] = ss[48 + c0b + j]; }
    }

    f32x4 acc[2] = {};
#pragma unroll
    for (int ci = 0; ci < 4; ++ci) {
        const int ch  = kg * 4 + ci;
        const int t   = ch >> 1;
        const int sub = ch & 1;
        const int idx = child[(size_t)rowA * 8 + t];
        uint4 au = make_uint4(0, 0, 0, 0);
        const int c0 = sub ? c0b : c0a;
        if (c0 < 48) {
            const float4 v0 = *(const float4*)(y2 + (size_t)idx * 48 + c0);
            const float4 v1 = *(const float4*)(y2 + (size_t)idx * 48 + c0 + 4);
            const float vv[8] = {v0.x, v0.y, v0.z, v0.w, v1.x, v1.y, v1.z, v1.w};
            const float* scp = sub ? scb : sca;
            const float* shp = sub ? shb : sha;
            unsigned int o4[4];
#pragma unroll
            for (int h = 0; h < 4; ++h) {
                const float a0 = fmaxf(vv[2 * h]     * scp[2 * h]     + shp[2 * h],     0.f);
                const float a1 = fmaxf(vv[2 * h + 1] * scp[2 * h + 1] + shp[2 * h + 1], 0.f);
                o4[h] = (unsigned)f2bf(a0) | ((unsigned)f2bf(a1) << 16);
            }
            au = make_uint4(o4[0], o4[1], o4[2], o4[3]);
        }
        const bf16x8 af = as_bf8(au);
#pragma unroll
        for (int ct = 0; ct < 2; ++ct) {
            const int n = (cg * 2 + ct) * 16 + l15;
            const uint4 bu = *(const uint4*)(Wb + ((size_t)ch * 96 + n) * 32 + quad * 8);
            acc[ct] = __builtin_amdgcn_mfma_f32_16x16x32_bf16(af, as_bf8(bu), acc[ct], 0, 0, 0);
        }
    }

    float* yo = yout + (size_t)kg * ystride;
#pragma unroll
    for (int ct = 0; ct < 2; ++ct) {
        const int col = (cg * 2 + ct) * 16 + l15;
#pragma unroll
        for (int r = 0; r < 4; ++r) {
            const int rr = blockIdx.x * 64 + wave * 16 + quad * 4 + r;
            yo[(size_t)rr * 96 + col] = acc[ct][r];
        }
    }
}

// ---------------- stats v2: vectorized partial-sum + moments + fused finalize ----------------
template<int C, int P, int NB>
__global__ __launch_bounds__(256) void stats2(
    const float* __restrict__ part, size_t pstride,
    float* __restrict__ yfull, int total, int M,
    const float* __restrict__ gamma_, const float* __restrict__ beta_,
    float* __restrict__ bins, int* __restrict__ counter, float* __restrict__ ss_out)
{
    __shared__ float lsq[2 * C];
    __shared__ int lastflag;
    const int tid = threadIdx.x;
    if (tid < 2 * C) lsq[tid] = 0.f;
    __syncthreads();

    float s4[4] = {0, 0, 0, 0}, q4[4] = {0, 0, 0, 0};
    int i = (blockIdx.x * 256 + tid) * 4;
    const int c0 = i % C;
    const int stride = gridDim.x * 1024;
    for (; i < total; i += stride) {
        float4 v = *(const float4*)(part + i);
#pragma unroll
        for (int p = 1; p < P; ++p) {
            const float4 w = *(const float4*)(part + (size_t)p * pstride + i);
            v.x += w.x; v.y += w.y; v.z += w.z; v.w += w.w;
        }
        *(float4*)(yfull + i) = v;
        s4[0] += v.x; q4[0] += v.x * v.x;
        s4[1] += v.y; q4[1] += v.y * v.y;
        s4[2] += v.z; q4[2] += v.z * v.z;
        s4[3] += v.w; q4[3] += v.w * v.w;
    }
#pragma unroll
    for (int j = 0; j < 4; ++j) {
        atomicAdd(&lsq[c0 + j], s4[j]);
        atomicAdd(&lsq[C + c0 + j], q4[j]);
    }
    __syncthreads();
    if (tid < 2 * C) atomicAdd(&bins[(blockIdx.x % NB) * 2 * C + tid], lsq[tid]);
    if (tid == 0) {
        __threadfence();
        int p = __hip_atomic_fetch_add(counter, 1, __ATOMIC_ACQ_REL, __HIP_MEMORY_SCOPE_AGENT);
        lastflag = (p == (int)gridDim.x - 1) ? 1 : 0;
    }
    __syncthreads();
    if (lastflag && tid < C) {
        float S = 0.f, Q = 0.f;
        for (int b2 = 0; b2 < NB; ++b2) {
            S += __hip_atomic_load(&bins[b2 * 2 * C + tid],     __ATOMIC_RELAXED, __HIP_MEMORY_SCOPE_AGENT);
            Q += __hip_atomic_load(&bins[b2 * 2 * C + C + tid], __ATOMIC_RELAXED, __HIP_MEMORY_SCOPE_AGENT);
        }
        const float mu  = S / (float)M;
        const float var = fmaxf(Q / (float)M - mu * mu, 0.f);
        const float scale = gamma_[tid] / sqrtf(var + EPSBN);
        ss_out[tid]     = scale;
        ss_out[C + tid] = beta_[tid] - mu * scale;
    }
}

// ---------------- activation: XB = bf16(relu(y*scale+shift)), zero pad cols ----------------
template<int C, int CP>
__global__ void activate_kernel(const float* __restrict__ y, const float* __restrict__ ss,
                                ush_t* __restrict__ xb, int totalP)
{
    int i = (blockIdx.x * blockDim.x + threadIdx.x) * 4;
    if (i >= totalP) return;
    const int c = i % CP;
    ushort4 o;
    if (CP != C && c >= C) {
        o.x = o.y = o.z = o.w = 0;
    } else {
        const int r = i / CP;
        float4 v = *(const float4*)(y + (size_t)r * C + c);
        o.x = f2bf(fmaxf(v.x * ss[c + 0] + ss[C + c + 0], 0.f));
        o.y = f2bf(fmaxf(v.y * ss[c + 1] + ss[C + c + 1], 0.f));
        o.z = f2bf(fmaxf(v.z * ss[c + 2] + ss[C + c + 2], 0.f));
        o.w = f2bf(fmaxf(v.w * ss[c + 3] + ss[C + c + 3], 0.f));
    }
    *(ushort4*)(xb + i) = o;
}

// ---------------- final write (f32 out) ----------------
__global__ void writeout_kernel(const float* __restrict__ y, const float* __restrict__ ss,
                                float* __restrict__ out, int total)
{
    int i = (blockIdx.x * blockDim.x + threadIdx.x) * 4;
    if (i >= total) return;
    float4 v = *(const float4*)(y + i);
    int c = i % 96;
    float4 o;
    o.x = fmaxf(v.x * ss[c + 0] + ss[96 + c + 0], 0.f);
    o.y = fmaxf(v.y * ss[c + 1] + ss[96 + c + 1], 0.f);
    o.z = fmaxf(v.z * ss[c + 2] + ss[96 + c + 2], 0.f);
    o.w = fmaxf(v.w * ss[c + 3] + ss[96 + c + 3], 0.f);
    *(float4*)(out + i) = o;
}

// ---------------- host ----------------
extern "C" void kernel_launch(void* const* d_in, const int* in_sizes, int n_in,
                              void* d_out, int out_size, void* d_ws, size_t ws_size,
                              hipStream_t stream)
{
    const float* data   = (const float*)d_in[0];
    const int*   neigh0 = (const int*)d_in[1];
    const int*   child0 = (const int*)d_in[2];
    const int*   neigh1 = (const int*)d_in[3];
    const int*   child1 = (const int*)d_in[4];
    const int*   neigh2 = (const int*)d_in[5];
    const float* w0  = (const float*)d_in[6];
    const float* g0  = (const float*)d_in[7];
    const float* b0  = (const float*)d_in[8];
    const float* wd0 = (const float*)d_in[9];
    const float* gd0 = (const float*)d_in[10];
    const float* bd0 = (const float*)d_in[11];
    const float* w1  = (const float*)d_in[12];
    const float* g1  = (const float*)d_in[13];
    const float* b1  = (const float*)d_in[14];
    const float* wd1 = (const float*)d_in[15];
    const float* gd1 = (const float*)d_in[16];
    const float* bd1 = (const float*)d_in[17];
    const float* wp  = (const float*)d_in[18];
    const float* gp  = (const float*)d_in[19];
    const float* bp  = (const float*)d_in[20];
    float* out = (float*)d_out;

    // header (float offsets)
    float* wsf = (float*)d_ws;
    int*   counters = (int*)d_ws;      // ints [0..8)
    float* binsA = wsf + 16;           // 16*48  -> 784
    float* binsB = wsf + 784;          // 16*96  -> 2320
    float* binsC = wsf + 2320;         //        -> 3856
    float* binsD = wsf + 3856;         // 16*192 -> 6928
    float* binsE = wsf + 6928;         //        -> 10000
    float* ss0 = wsf + 10000;
    float* ss1 = wsf + 10064;
    float* ss2 = wsf + 10176;
    float* ss3 = wsf + 10288;
    float* ss4 = wsf + 10480;          // ends 10672, pad 10752

    // arena
    float* YF   = wsf + 10752;                         // 1,572,864 f (y1/y2/y3/y4)
    float* PART = YF + (size_t)1572864;                // 3,538,944 f (partials)
    ush_t* Y0B  = (ush_t*)(PART + (size_t)3538944);    // 6,291,456 ush: y0 bf16 [N0,24]
    ush_t* XB   = Y0B + (size_t)6291456;               // 2,097,152 ush: bf16 activ.
    ush_t* XA   = XB + (size_t)2097152;                // 1,048,576 ush: packed input [N0,4]
    ush_t* WB   = XA + (size_t)1048576;                //   524,288 ush: prepped weights

    ush_t* wbA = WB;
    ush_t* wbB = WB + 4096;
    ush_t* wbC = WB + 16384;
    ush_t* wbD = WB + 99328;
    ush_t* wbE = WB + 148480;

    hipMemsetAsync(d_ws, 0, 10752 * sizeof(float), stream);

    const size_t s1 = (size_t)N1 * 48;
    const size_t s2 = (size_t)N2 * 96;

    prep_weights<<<dim3(972, 5), 256, 0, stream>>>(w0, wd0, w1, wd1, wp, wbA, wbB, wbC, wbD, wbE);
    prep_input<<<N0 / 256, 256, 0, stream>>>(data, XA, N0);

    // stage A: conv -> Y0B (bf16 pre-BN); small-grid stats -> ss0
    mconvA<<<N0 / 64, 256, 0, stream>>>(XA, neigh0, wbA, Y0B);
    statsA<<<384, 256, 0, stream>>>(Y0B, g0, b0, binsA, &counters[0], ss0);

    // stage B: fused activate(y0,ss0) gather -> partials(2); stats -> y1 (YF), ss1; activate -> XB
    mconvB<<<dim3(N1 / 64, 2, 1), 256, 0, stream>>>(Y0B, ss0, child0, wbB, PART, s1);
    stats2<48, 2, 16><<<384, 256, 0, stream>>>(PART, s1, YF, N1 * 48, N1, gd0, bd0, binsB, &counters[1], ss1);
    activate_kernel<48, 64><<<N1 * 64 / 4 / 256, 256, 0, stream>>>(YF, ss1, XB, N1 * 64);

    // stage C: XB -> partials(2); stats -> y2 (YF), ss2
    mconv<27, 48, 64, 48, 48, 54, 2, 1><<<dim3(N1 / 64, 2, 1), 256, 0, stream>>>(XB, neigh1, wbC, PART, s1, N1);
    stats2<48, 2, 16><<<384, 256, 0, stream>>>(PART, s1, YF, N1 * 48, N1, g1, b1, binsC, &counters[2], ss2);

    // stage D: fused activate(y2,ss2) gather -> partials(4); stats -> y3 (YF), ss3; activate -> XB
    mconvD<<<dim3(N2 / 64, 4, 3), 256, 0, stream>>>(YF, ss2, child1, wbD, PART, s2);
    stats2<96, 4, 16><<<384, 256, 0, stream>>>(PART, s2, YF, N2 * 96, N2, gd1, bd1, binsD, &counters[3], ss3);
    activate_kernel<96, 96><<<N2 * 96 / 4 / 256, 256, 0, stream>>>(YF, ss3, XB, N2 * 96);

    // stage E: XB -> partials(9); stats -> y4 (YF), ss4
    mconv<27, 96, 96, 96, 96, 81, 9, 2><<<dim3(N2 / 64, 9, 2), 256, 0, stream>>>(XB, neigh2, wbE, PART, s2, N2);
    stats2<96, 9, 16><<<384, 256, 0, stream>>>(PART, s2, YF, N2 * 96, N2, gp, bp, binsE, &counters[4], ss4);

    // final normalize + relu -> out
    writeout_kernel<<<N2 * 96 / 4 / 256, 256, 0, stream>>>(YF, ss4, out, N2 * 96);

    (void)in_sizes; (void)n_in; (void)out_size; (void)ws_size;
}